// Round 1
// baseline (2417.692 us; speedup 1.0000x reference)
//
#include <hip/hip_runtime.h>
#include <hip/hip_bf16.h>
#include <math.h>

// Problem constants (fixed by the reference)
#define N_NODES 50000
#define N_EDGES 800000
#define NODE_DIM 3
#define EDGE_DIM 32
#define HIDDEN 128
#define NUM_GRAPHS 256
#define ZIN (2*HIDDEN + EDGE_DIM)   // 288

// ---------------------------------------------------------------------------
// conv1: CGConv on 3-dim features. One thread per edge.
// z = [x[dst](3) | x[src](3) | e(32)]  (38)
// msg = sigmoid(z@Wf1+bf1) * softplus(z@Ws1+bs1)   -> atomicAdd to agg0[dst]
// ---------------------------------------------------------------------------
__global__ __launch_bounds__(256) void conv1_kernel(
    const float* __restrict__ x, const int* __restrict__ ei,
    const float* __restrict__ EA,
    const float* __restrict__ Wf1, const float* __restrict__ bf1,
    const float* __restrict__ Ws1, const float* __restrict__ bs1,
    float* __restrict__ agg0)
{
    __shared__ float WfL[38*3], WsL[38*3], bfL[3], bsL[3];
    if (threadIdx.x < 114) {
        WfL[threadIdx.x] = Wf1[threadIdx.x];
        WsL[threadIdx.x] = Ws1[threadIdx.x];
    }
    if (threadIdx.x < 3) { bfL[threadIdx.x] = bf1[threadIdx.x]; bsL[threadIdx.x] = bs1[threadIdx.x]; }
    __syncthreads();

    int e = blockIdx.x * 256 + threadIdx.x;
    if (e >= N_EDGES) return;
    int s = ei[e];
    int d = ei[N_EDGES + e];

    float z[38];
    z[0] = x[d*3+0]; z[1] = x[d*3+1]; z[2] = x[d*3+2];
    z[3] = x[s*3+0]; z[4] = x[s*3+1]; z[5] = x[s*3+2];
    const float4* ep = (const float4*)(EA + (size_t)e * EDGE_DIM);
    #pragma unroll
    for (int q = 0; q < 8; ++q) {
        float4 v = ep[q];
        z[6+4*q+0] = v.x; z[6+4*q+1] = v.y; z[6+4*q+2] = v.z; z[6+4*q+3] = v.w;
    }
    float f[3], g[3];
    #pragma unroll
    for (int c = 0; c < 3; ++c) { f[c] = bfL[c]; g[c] = bsL[c]; }
    #pragma unroll
    for (int j = 0; j < 38; ++j) {
        #pragma unroll
        for (int c = 0; c < 3; ++c) {
            f[c] += z[j] * WfL[j*3+c];
            g[c] += z[j] * WsL[j*3+c];
        }
    }
    #pragma unroll
    for (int c = 0; c < 3; ++c) {
        float sig = 1.0f / (1.0f + __expf(-f[c]));
        float sp  = fmaxf(g[c], 0.0f) + log1pf(__expf(-fabsf(g[c])));
        atomicAdd(agg0 + (size_t)d*3 + c, sig * sp);
    }
}

// ---------------------------------------------------------------------------
// proj: H[n][c] = relu(bp[c] + sum_j (x[n][j]+agg0[n][j]) * Wp[j][c])
// ---------------------------------------------------------------------------
__global__ __launch_bounds__(256) void proj_kernel(
    const float* __restrict__ x, const float* __restrict__ agg0,
    const float* __restrict__ Wp, const float* __restrict__ bp,
    float* __restrict__ H)
{
    int idx = blockIdx.x * 256 + threadIdx.x;
    if (idx >= N_NODES * HIDDEN) return;
    int n = idx >> 7, c = idx & 127;
    float h0 = x[n*3+0] + agg0[n*3+0];
    float h1 = x[n*3+1] + agg0[n*3+1];
    float h2 = x[n*3+2] + agg0[n*3+2];
    float v = bp[c] + h0*Wp[0*128+c] + h1*Wp[1*128+c] + h2*Wp[2*128+c];
    H[idx] = fmaxf(v, 0.0f);
}

// ---------------------------------------------------------------------------
// Repack layer weights into Wcat (128 x 512), cols: [f_dst | f_src | s_dst | s_src]
// Wf/Ws are (2, 288, 128); rows 0..127 = dst part, 128..255 = src part.
// ---------------------------------------------------------------------------
__global__ __launch_bounds__(256) void repack_kernel(
    const float* __restrict__ Wf, const float* __restrict__ Ws,
    float* __restrict__ Wcat)
{
    int idx = blockIdx.x * 256 + threadIdx.x;   // 2 * 128 * 512 total
    if (idx >= 2*128*512) return;
    int l = idx >> 16;
    int rem = idx & 65535;
    int k = rem >> 9, n = rem & 511;
    const float* wf = Wf + (size_t)l * ZIN * HIDDEN;
    const float* wsp = Ws + (size_t)l * ZIN * HIDDEN;
    float v;
    if      (n < 128) v = wf[(size_t)k*128 + n];
    else if (n < 256) v = wf[(size_t)(128+k)*128 + (n-128)];
    else if (n < 384) v = wsp[(size_t)k*128 + (n-256)];
    else              v = wsp[(size_t)(128+k)*128 + (n-384)];
    Wcat[idx] = v;
}

// ---------------------------------------------------------------------------
// GEMM: C(MxN) = A(MxK) @ B(KxN), fp32, 64x64 tile, 4x4 per thread, k-step 16
// ---------------------------------------------------------------------------
__global__ __launch_bounds__(256) void gemm64(
    const float* __restrict__ A, const float* __restrict__ B,
    float* __restrict__ C, int M, int N, int K)
{
    __shared__ float As[16][65];
    __shared__ float Bs[16][65];
    const int tid = threadIdx.x;
    const int tx = tid & 15;
    const int ty = tid >> 4;
    const int colBase = blockIdx.x * 64;
    const int rowBase = blockIdx.y * 64;
    const int am = tid >> 2;          // 0..63
    const int ak = (tid & 3) * 4;     // 0,4,8,12
    const int bk = tid >> 4;          // 0..15
    const int bn = (tid & 15) * 4;

    float acc[4][4];
    #pragma unroll
    for (int i = 0; i < 4; ++i)
        #pragma unroll
        for (int j = 0; j < 4; ++j) acc[i][j] = 0.0f;

    for (int k0 = 0; k0 < K; k0 += 16) {
        int arow = rowBase + am;
        float4 a4 = make_float4(0.f, 0.f, 0.f, 0.f);
        if (arow < M) a4 = *(const float4*)(A + (size_t)arow * K + k0 + ak);
        float4 b4 = *(const float4*)(B + (size_t)(k0 + bk) * N + colBase + bn);
        __syncthreads();
        As[ak+0][am] = a4.x; As[ak+1][am] = a4.y; As[ak+2][am] = a4.z; As[ak+3][am] = a4.w;
        Bs[bk][bn+0] = b4.x; Bs[bk][bn+1] = b4.y; Bs[bk][bn+2] = b4.z; Bs[bk][bn+3] = b4.w;
        __syncthreads();
        #pragma unroll
        for (int k = 0; k < 16; ++k) {
            float a0 = As[k][ty*4+0], a1 = As[k][ty*4+1], a2 = As[k][ty*4+2], a3 = As[k][ty*4+3];
            float b0 = Bs[k][tx*4+0], b1 = Bs[k][tx*4+1], b2 = Bs[k][tx*4+2], b3 = Bs[k][tx*4+3];
            acc[0][0] += a0*b0; acc[0][1] += a0*b1; acc[0][2] += a0*b2; acc[0][3] += a0*b3;
            acc[1][0] += a1*b0; acc[1][1] += a1*b1; acc[1][2] += a1*b2; acc[1][3] += a1*b3;
            acc[2][0] += a2*b0; acc[2][1] += a2*b1; acc[2][2] += a2*b2; acc[2][3] += a2*b3;
            acc[3][0] += a3*b0; acc[3][1] += a3*b1; acc[3][2] += a3*b2; acc[3][3] += a3*b3;
        }
    }
    #pragma unroll
    for (int i = 0; i < 4; ++i) {
        int r = rowBase + ty*4 + i;
        if (r >= M) continue;
        #pragma unroll
        for (int j = 0; j < 4; ++j) {
            C[(size_t)r * N + colBase + tx*4 + j] = acc[i][j];
        }
    }
}

// ---------------------------------------------------------------------------
// Fused edge kernel for the 128-dim CGConv layers.
// 128 threads per edge (2 edges per 256-thread block); edge-weight columns
// held in registers (32 f + 32 s per lane). Grid-stride over edges.
// f = bf[c] + P[dst][c]     + P[src][128+c] + e @ Wf_e[:,c]
// g = bs[c] + P[dst][256+c] + P[src][384+c] + e @ Ws_e[:,c]
// agg[dst][c] += sigmoid(f) * softplus(g)
// ---------------------------------------------------------------------------
__global__ __launch_bounds__(256) void edge_kernel(
    const float* __restrict__ P, const float* __restrict__ EA,
    const int* __restrict__ ei,
    const float* __restrict__ Wfe, const float* __restrict__ Wse,  // (32,128) each
    const float* __restrict__ bf, const float* __restrict__ bs,
    float* __restrict__ agg)
{
    const int c = threadIdx.x & 127;
    const int sub = threadIdx.x >> 7;
    float wf[32], ws[32];
    #pragma unroll
    for (int k = 0; k < 32; ++k) { wf[k] = Wfe[k*128 + c]; ws[k] = Wse[k*128 + c]; }
    const float bfc = bf[c], bsc = bs[c];
    const int stride = gridDim.x * 2;
    const int* srcA = ei;
    const int* dstA = ei + N_EDGES;

    for (int e = blockIdx.x * 2 + sub; e < N_EDGES; e += stride) {
        int s = srcA[e];
        int d = dstA[e];
        const float4* ep = (const float4*)(EA + (size_t)e * EDGE_DIM);
        float ev[32];
        #pragma unroll
        for (int q = 0; q < 8; ++q) {
            float4 v = ep[q];
            ev[4*q+0] = v.x; ev[4*q+1] = v.y; ev[4*q+2] = v.z; ev[4*q+3] = v.w;
        }
        const float* Pd = P + (size_t)d * 512;
        const float* Ps = P + (size_t)s * 512;
        float f = bfc + Pd[c]       + Ps[128 + c];
        float g = bsc + Pd[256 + c] + Ps[384 + c];
        #pragma unroll
        for (int k = 0; k < 32; ++k) {
            f += ev[k] * wf[k];
            g += ev[k] * ws[k];
        }
        float sig = 1.0f / (1.0f + __expf(-f));
        float sp  = fmaxf(g, 0.0f) + log1pf(__expf(-fabsf(g)));
        atomicAdd(agg + (size_t)d * HIDDEN + c, sig * sp);
    }
}

// ---------------------------------------------------------------------------
// H = relu(H + agg)
// ---------------------------------------------------------------------------
__global__ __launch_bounds__(256) void update_kernel(
    float* __restrict__ H, const float* __restrict__ agg)
{
    int idx = blockIdx.x * 256 + threadIdx.x;
    if (idx >= N_NODES * HIDDEN) return;
    H[idx] = fmaxf(H[idx] + agg[idx], 0.0f);
}

// ---------------------------------------------------------------------------
// Pool: per-graph sums + counts. batch is sorted; run-length accumulate then
// one atomic per (graph-run, col).
// Block = 128 threads handling 128 consecutive nodes.
// ---------------------------------------------------------------------------
__global__ __launch_bounds__(128) void pool_kernel(
    const float* __restrict__ H, const int* __restrict__ batch,
    float* __restrict__ gsum, float* __restrict__ gcnt)
{
    const int c = threadIdx.x;
    const int n0 = blockIdx.x * 128;
    float acc = 0.0f;
    int cur = -1;
    for (int i = 0; i < 128; ++i) {
        int n = n0 + i;
        if (n >= N_NODES) break;
        int g = batch[n];
        if (g != cur) {
            if (cur >= 0) atomicAdd(gsum + (size_t)cur * HIDDEN + c, acc);
            cur = g; acc = 0.0f;
        }
        acc += H[(size_t)n * HIDDEN + c];
    }
    if (cur >= 0) atomicAdd(gsum + (size_t)cur * HIDDEN + c, acc);

    if (c == 0) {
        int curg = -1; float run = 0.0f;
        for (int i = 0; i < 128; ++i) {
            int n = n0 + i;
            if (n >= N_NODES) break;
            int g = batch[n];
            if (g != curg) {
                if (curg >= 0) atomicAdd(gcnt + curg, run);
                curg = g; run = 0.0f;
            }
            run += 1.0f;
        }
        if (curg >= 0) atomicAdd(gcnt + curg, run);
    }
}

// ---------------------------------------------------------------------------
// Final MLP: g = relu((gsum/cnt) @ W1 + b1); out = g @ Wh^T + bh
// One block (128 threads) per graph.
// ---------------------------------------------------------------------------
__global__ __launch_bounds__(128) void head_kernel(
    const float* __restrict__ gsum, const float* __restrict__ gcnt,
    const float* __restrict__ W1, const float* __restrict__ b1,
    const float* __restrict__ Wh, const float* __restrict__ bh,
    float* __restrict__ out)
{
    __shared__ float gavg[128];
    __shared__ float g1[128];
    const int g = blockIdx.x, c = threadIdx.x;
    float cnt = fmaxf(gcnt[g], 1.0f);
    gavg[c] = gsum[(size_t)g * HIDDEN + c] / cnt;
    __syncthreads();
    float acc = b1[c];
    for (int k = 0; k < 128; ++k) acc += gavg[k] * W1[k*128 + c];
    g1[c] = fmaxf(acc, 0.0f);
    __syncthreads();
    if (c < 5) {
        float o = bh[c];
        for (int k = 0; k < 128; ++k) o += g1[k] * Wh[c*128 + k];
        out[(size_t)g * 5 + c] = o;
    }
}

// ---------------------------------------------------------------------------
// Launch
// ---------------------------------------------------------------------------
extern "C" void kernel_launch(void* const* d_in, const int* in_sizes, int n_in,
                              void* d_out, int out_size, void* d_ws, size_t ws_size,
                              hipStream_t stream) {
    const float* x        = (const float*)d_in[0];
    const int*   ei       = (const int*)  d_in[1];
    const float* EA       = (const float*)d_in[2];
    const int*   batch    = (const int*)  d_in[3];
    const float* Wf1      = (const float*)d_in[4];
    const float* bf1      = (const float*)d_in[5];
    const float* Ws1      = (const float*)d_in[6];
    const float* bs1      = (const float*)d_in[7];
    const float* Wp       = (const float*)d_in[8];
    const float* bp       = (const float*)d_in[9];
    const float* Wf_convs = (const float*)d_in[10];
    const float* bf_convs = (const float*)d_in[11];
    const float* Ws_convs = (const float*)d_in[12];
    const float* bs_convs = (const float*)d_in[13];
    const float* W1       = (const float*)d_in[14];
    const float* b1       = (const float*)d_in[15];
    const float* W_heads  = (const float*)d_in[16];
    const float* b_heads  = (const float*)d_in[17];
    float* out = (float*)d_out;

    float* ws = (float*)d_ws;
    // workspace layout (floats), offsets 64-aligned
    float* agg0 = ws + 0;                       // 150000
    float* H    = ws + 150016;                  // 6,400,000
    float* P    = ws + 6550016;                 // 25,600,000
    float* agg  = ws + 32150016;                // 6,400,000
    float* Wcat = ws + 38550016;                // 131072 (2 layers x 128 x 512)
    float* gsum = ws + 38681088;                // 32768
    float* gcnt = ws + 38713856;                // 256

    // conv1
    hipMemsetAsync(agg0, 0, (size_t)N_NODES * 3 * sizeof(float), stream);
    conv1_kernel<<<(N_EDGES + 255)/256, 256, 0, stream>>>(x, ei, EA, Wf1, bf1, Ws1, bs1, agg0);
    // proj
    proj_kernel<<<(N_NODES*HIDDEN + 255)/256, 256, 0, stream>>>(x, agg0, Wp, bp, H);
    // repack weights for both layers
    repack_kernel<<<(2*128*512 + 255)/256, 256, 0, stream>>>(Wf_convs, Ws_convs, Wcat);

    for (int l = 0; l < 2; ++l) {
        const float* Wcat_l = Wcat + (size_t)l * 128 * 512;
        const float* Wfe = Wf_convs + (size_t)l * ZIN * HIDDEN + 256*128;
        const float* Wse = Ws_convs + (size_t)l * ZIN * HIDDEN + 256*128;
        const float* bfl = bf_convs + (size_t)l * HIDDEN;
        const float* bsl = bs_convs + (size_t)l * HIDDEN;
        // P = H @ Wcat_l  (50000 x 128 x 512)
        dim3 ggrid(512/64, (N_NODES + 63)/64);
        gemm64<<<ggrid, 256, 0, stream>>>(H, Wcat_l, P, N_NODES, 512, 128);
        // agg = 0; edge messages
        hipMemsetAsync(agg, 0, (size_t)N_NODES * HIDDEN * sizeof(float), stream);
        edge_kernel<<<2048, 256, 0, stream>>>(P, EA, ei, Wfe, Wse, bfl, bsl, agg);
        // H = relu(H + agg)
        update_kernel<<<(N_NODES*HIDDEN + 255)/256, 256, 0, stream>>>(H, agg);
    }

    // pool + heads
    hipMemsetAsync(gsum, 0, (size_t)(NUM_GRAPHS * HIDDEN + NUM_GRAPHS) * sizeof(float), stream);
    pool_kernel<<<(N_NODES + 127)/128, 128, 0, stream>>>(H, batch, gsum, gcnt);
    head_kernel<<<NUM_GRAPHS, 128, 0, stream>>>(gsum, gcnt, W1, b1, W_heads, b_heads, out);
}

// Round 2
// 1737.614 us; speedup vs baseline: 1.3914x; 1.3914x over previous
//
#include <hip/hip_runtime.h>
#include <hip/hip_bf16.h>
#include <math.h>

// Problem constants (fixed by the reference)
#define N_NODES 50000
#define N_EDGES 800000
#define NODE_DIM 3
#define EDGE_DIM 32
#define HIDDEN 128
#define NUM_GRAPHS 256
#define ZIN (2*HIDDEN + EDGE_DIM)   // 288

// ---------------------------------------------------------------------------
// conv1: CGConv on 3-dim features. One thread per edge.
// ---------------------------------------------------------------------------
__global__ __launch_bounds__(256) void conv1_kernel(
    const float* __restrict__ x, const int* __restrict__ ei,
    const float* __restrict__ EA,
    const float* __restrict__ Wf1, const float* __restrict__ bf1,
    const float* __restrict__ Ws1, const float* __restrict__ bs1,
    float* __restrict__ agg0)
{
    __shared__ float WfL[38*3], WsL[38*3], bfL[3], bsL[3];
    if (threadIdx.x < 114) {
        WfL[threadIdx.x] = Wf1[threadIdx.x];
        WsL[threadIdx.x] = Ws1[threadIdx.x];
    }
    if (threadIdx.x < 3) { bfL[threadIdx.x] = bf1[threadIdx.x]; bsL[threadIdx.x] = bs1[threadIdx.x]; }
    __syncthreads();

    int e = blockIdx.x * 256 + threadIdx.x;
    if (e >= N_EDGES) return;
    int s = ei[e];
    int d = ei[N_EDGES + e];

    float z[38];
    z[0] = x[d*3+0]; z[1] = x[d*3+1]; z[2] = x[d*3+2];
    z[3] = x[s*3+0]; z[4] = x[s*3+1]; z[5] = x[s*3+2];
    const float4* ep = (const float4*)(EA + (size_t)e * EDGE_DIM);
    #pragma unroll
    for (int q = 0; q < 8; ++q) {
        float4 v = ep[q];
        z[6+4*q+0] = v.x; z[6+4*q+1] = v.y; z[6+4*q+2] = v.z; z[6+4*q+3] = v.w;
    }
    float f[3], g[3];
    #pragma unroll
    for (int c = 0; c < 3; ++c) { f[c] = bfL[c]; g[c] = bsL[c]; }
    #pragma unroll
    for (int j = 0; j < 38; ++j) {
        #pragma unroll
        for (int c = 0; c < 3; ++c) {
            f[c] += z[j] * WfL[j*3+c];
            g[c] += z[j] * WsL[j*3+c];
        }
    }
    #pragma unroll
    for (int c = 0; c < 3; ++c) {
        float sig = __builtin_amdgcn_rcpf(1.0f + __expf(-f[c]));
        float sp  = fmaxf(g[c], 0.0f) + __logf(1.0f + __expf(-fabsf(g[c])));
        atomicAdd(agg0 + (size_t)d*3 + c, sig * sp);
    }
}

// ---------------------------------------------------------------------------
// proj: H[n][c] = relu(bp[c] + sum_j (x[n][j]+agg0[n][j]) * Wp[j][c])
// ---------------------------------------------------------------------------
__global__ __launch_bounds__(256) void proj_kernel(
    const float* __restrict__ x, const float* __restrict__ agg0,
    const float* __restrict__ Wp, const float* __restrict__ bp,
    float* __restrict__ H)
{
    int idx = blockIdx.x * 256 + threadIdx.x;
    if (idx >= N_NODES * HIDDEN) return;
    int n = idx >> 7, c = idx & 127;
    float h0 = x[n*3+0] + agg0[n*3+0];
    float h1 = x[n*3+1] + agg0[n*3+1];
    float h2 = x[n*3+2] + agg0[n*3+2];
    float v = bp[c] + h0*Wp[0*128+c] + h1*Wp[1*128+c] + h2*Wp[2*128+c];
    H[idx] = fmaxf(v, 0.0f);
}

// ---------------------------------------------------------------------------
// Repack layer weights into Wcat (128 x 512), cols: [f_dst | f_src | s_dst | s_src]
// ---------------------------------------------------------------------------
__global__ __launch_bounds__(256) void repack_kernel(
    const float* __restrict__ Wf, const float* __restrict__ Ws,
    float* __restrict__ Wcat)
{
    int idx = blockIdx.x * 256 + threadIdx.x;   // 2 * 128 * 512 total
    if (idx >= 2*128*512) return;
    int l = idx >> 16;
    int rem = idx & 65535;
    int k = rem >> 9, n = rem & 511;
    const float* wf = Wf + (size_t)l * ZIN * HIDDEN;
    const float* wsp = Ws + (size_t)l * ZIN * HIDDEN;
    float v;
    if      (n < 128) v = wf[(size_t)k*128 + n];
    else if (n < 256) v = wf[(size_t)(128+k)*128 + (n-128)];
    else if (n < 384) v = wsp[(size_t)k*128 + (n-256)];
    else              v = wsp[(size_t)(128+k)*128 + (n-384)];
    Wcat[idx] = v;
}

// ---------------------------------------------------------------------------
// GEMM: C(MxN) = A(MxK) @ B(KxN), fp32, 64x64 tile, 4x4 per thread, k-step 16
// ---------------------------------------------------------------------------
__global__ __launch_bounds__(256) void gemm64(
    const float* __restrict__ A, const float* __restrict__ B,
    float* __restrict__ C, int M, int N, int K)
{
    __shared__ float As[16][65];
    __shared__ float Bs[16][65];
    const int tid = threadIdx.x;
    const int tx = tid & 15;
    const int ty = tid >> 4;
    const int colBase = blockIdx.x * 64;
    const int rowBase = blockIdx.y * 64;
    const int am = tid >> 2;          // 0..63
    const int ak = (tid & 3) * 4;     // 0,4,8,12
    const int bk = tid >> 4;          // 0..15
    const int bn = (tid & 15) * 4;

    float acc[4][4];
    #pragma unroll
    for (int i = 0; i < 4; ++i)
        #pragma unroll
        for (int j = 0; j < 4; ++j) acc[i][j] = 0.0f;

    for (int k0 = 0; k0 < K; k0 += 16) {
        int arow = rowBase + am;
        float4 a4 = make_float4(0.f, 0.f, 0.f, 0.f);
        if (arow < M) a4 = *(const float4*)(A + (size_t)arow * K + k0 + ak);
        float4 b4 = *(const float4*)(B + (size_t)(k0 + bk) * N + colBase + bn);
        __syncthreads();
        As[ak+0][am] = a4.x; As[ak+1][am] = a4.y; As[ak+2][am] = a4.z; As[ak+3][am] = a4.w;
        Bs[bk][bn+0] = b4.x; Bs[bk][bn+1] = b4.y; Bs[bk][bn+2] = b4.z; Bs[bk][bn+3] = b4.w;
        __syncthreads();
        #pragma unroll
        for (int k = 0; k < 16; ++k) {
            float a0 = As[k][ty*4+0], a1 = As[k][ty*4+1], a2 = As[k][ty*4+2], a3 = As[k][ty*4+3];
            float b0 = Bs[k][tx*4+0], b1 = Bs[k][tx*4+1], b2 = Bs[k][tx*4+2], b3 = Bs[k][tx*4+3];
            acc[0][0] += a0*b0; acc[0][1] += a0*b1; acc[0][2] += a0*b2; acc[0][3] += a0*b3;
            acc[1][0] += a1*b0; acc[1][1] += a1*b1; acc[1][2] += a1*b2; acc[1][3] += a1*b3;
            acc[2][0] += a2*b0; acc[2][1] += a2*b1; acc[2][2] += a2*b2; acc[2][3] += a2*b3;
            acc[3][0] += a3*b0; acc[3][1] += a3*b1; acc[3][2] += a3*b2; acc[3][3] += a3*b3;
        }
    }
    #pragma unroll
    for (int i = 0; i < 4; ++i) {
        int r = rowBase + ty*4 + i;
        if (r >= M) continue;
        #pragma unroll
        for (int j = 0; j < 4; ++j) {
            C[(size_t)r * N + colBase + tx*4 + j] = acc[i][j];
        }
    }
}

// ---------------------------------------------------------------------------
// Fused edge kernel for the 128-dim CGConv layers.
// 128 threads per edge (2 edges per 256-thread block); edge-weight columns
// PINNED in registers (32 f + 32 s per lane) — __launch_bounds__(256,4)
// allows 128 VGPRs/wave so the compiler keeps them resident.
// Edge-attr float4s are consumed immediately (only 4 live at a time).
// Fast transcendentals: v_exp_f32 / v_log_f32 / v_rcp_f32.
// ---------------------------------------------------------------------------
__global__ __launch_bounds__(256, 4) void edge_kernel(
    const float* __restrict__ P, const float* __restrict__ EA,
    const int* __restrict__ ei,
    const float* __restrict__ Wfe, const float* __restrict__ Wse,  // (32,128) each
    const float* __restrict__ bf, const float* __restrict__ bs,
    float* __restrict__ agg)
{
    const int c = threadIdx.x & 127;
    const int sub = threadIdx.x >> 7;
    float wf[32], ws[32];
    #pragma unroll
    for (int k = 0; k < 32; ++k) { wf[k] = Wfe[k*128 + c]; ws[k] = Wse[k*128 + c]; }
    const float bfc = bf[c], bsc = bs[c];
    const int stride = gridDim.x * 2;
    const int* srcA = ei;
    const int* dstA = ei + N_EDGES;

    for (int e = blockIdx.x * 2 + sub; e < N_EDGES; e += stride) {
        int s = srcA[e];
        int d = dstA[e];
        const float4* ep = (const float4*)(EA + (size_t)e * EDGE_DIM);
        const float* Pd = P + (size_t)d * 512;
        const float* Ps = P + (size_t)s * 512;
        float f = bfc + Pd[c]       + Ps[128 + c];
        float g = bsc + Pd[256 + c] + Ps[384 + c];
        #pragma unroll
        for (int q = 0; q < 8; ++q) {
            float4 v = ep[q];
            f += v.x*wf[4*q+0] + v.y*wf[4*q+1] + v.z*wf[4*q+2] + v.w*wf[4*q+3];
            g += v.x*ws[4*q+0] + v.y*ws[4*q+1] + v.z*ws[4*q+2] + v.w*ws[4*q+3];
        }
        float sig = __builtin_amdgcn_rcpf(1.0f + __expf(-f));
        float sp  = fmaxf(g, 0.0f) + __logf(1.0f + __expf(-fabsf(g)));
        atomicAdd(agg + (size_t)d * HIDDEN + c, sig * sp);
    }
}

// ---------------------------------------------------------------------------
// H = relu(H + agg)
// ---------------------------------------------------------------------------
__global__ __launch_bounds__(256) void update_kernel(
    float* __restrict__ H, const float* __restrict__ agg)
{
    int idx = blockIdx.x * 256 + threadIdx.x;
    if (idx >= N_NODES * HIDDEN) return;
    H[idx] = fmaxf(H[idx] + agg[idx], 0.0f);
}

// ---------------------------------------------------------------------------
// Pool: per-graph sums + counts (batch sorted; run-length then atomic).
// ---------------------------------------------------------------------------
__global__ __launch_bounds__(128) void pool_kernel(
    const float* __restrict__ H, const int* __restrict__ batch,
    float* __restrict__ gsum, float* __restrict__ gcnt)
{
    const int c = threadIdx.x;
    const int n0 = blockIdx.x * 128;
    float acc = 0.0f;
    int cur = -1;
    for (int i = 0; i < 128; ++i) {
        int n = n0 + i;
        if (n >= N_NODES) break;
        int g = batch[n];
        if (g != cur) {
            if (cur >= 0) atomicAdd(gsum + (size_t)cur * HIDDEN + c, acc);
            cur = g; acc = 0.0f;
        }
        acc += H[(size_t)n * HIDDEN + c];
    }
    if (cur >= 0) atomicAdd(gsum + (size_t)cur * HIDDEN + c, acc);

    if (c == 0) {
        int curg = -1; float run = 0.0f;
        for (int i = 0; i < 128; ++i) {
            int n = n0 + i;
            if (n >= N_NODES) break;
            int g = batch[n];
            if (g != curg) {
                if (curg >= 0) atomicAdd(gcnt + curg, run);
                curg = g; run = 0.0f;
            }
            run += 1.0f;
        }
        if (curg >= 0) atomicAdd(gcnt + curg, run);
    }
}

// ---------------------------------------------------------------------------
// Final MLP: g = relu((gsum/cnt) @ W1 + b1); out = g @ Wh^T + bh
// ---------------------------------------------------------------------------
__global__ __launch_bounds__(128) void head_kernel(
    const float* __restrict__ gsum, const float* __restrict__ gcnt,
    const float* __restrict__ W1, const float* __restrict__ b1,
    const float* __restrict__ Wh, const float* __restrict__ bh,
    float* __restrict__ out)
{
    __shared__ float gavg[128];
    __shared__ float g1[128];
    const int g = blockIdx.x, c = threadIdx.x;
    float cnt = fmaxf(gcnt[g], 1.0f);
    gavg[c] = gsum[(size_t)g * HIDDEN + c] / cnt;
    __syncthreads();
    float acc = b1[c];
    for (int k = 0; k < 128; ++k) acc += gavg[k] * W1[k*128 + c];
    g1[c] = fmaxf(acc, 0.0f);
    __syncthreads();
    if (c < 5) {
        float o = bh[c];
        for (int k = 0; k < 128; ++k) o += g1[k] * Wh[c*128 + k];
        out[(size_t)g * 5 + c] = o;
    }
}

// ---------------------------------------------------------------------------
// Launch
// ---------------------------------------------------------------------------
extern "C" void kernel_launch(void* const* d_in, const int* in_sizes, int n_in,
                              void* d_out, int out_size, void* d_ws, size_t ws_size,
                              hipStream_t stream) {
    const float* x        = (const float*)d_in[0];
    const int*   ei       = (const int*)  d_in[1];
    const float* EA       = (const float*)d_in[2];
    const int*   batch    = (const int*)  d_in[3];
    const float* Wf1      = (const float*)d_in[4];
    const float* bf1      = (const float*)d_in[5];
    const float* Ws1      = (const float*)d_in[6];
    const float* bs1      = (const float*)d_in[7];
    const float* Wp       = (const float*)d_in[8];
    const float* bp       = (const float*)d_in[9];
    const float* Wf_convs = (const float*)d_in[10];
    const float* bf_convs = (const float*)d_in[11];
    const float* Ws_convs = (const float*)d_in[12];
    const float* bs_convs = (const float*)d_in[13];
    const float* W1       = (const float*)d_in[14];
    const float* b1       = (const float*)d_in[15];
    const float* W_heads  = (const float*)d_in[16];
    const float* b_heads  = (const float*)d_in[17];
    float* out = (float*)d_out;

    float* ws = (float*)d_ws;
    // workspace layout (floats), offsets 64-aligned
    float* agg0 = ws + 0;                       // 150000
    float* H    = ws + 150016;                  // 6,400,000
    float* P    = ws + 6550016;                 // 25,600,000
    float* agg  = ws + 32150016;                // 6,400,000
    float* Wcat = ws + 38550016;                // 131072 (2 layers x 128 x 512)
    float* gsum = ws + 38681088;                // 32768
    float* gcnt = ws + 38713856;                // 256

    // conv1
    hipMemsetAsync(agg0, 0, (size_t)N_NODES * 3 * sizeof(float), stream);
    conv1_kernel<<<(N_EDGES + 255)/256, 256, 0, stream>>>(x, ei, EA, Wf1, bf1, Ws1, bs1, agg0);
    // proj
    proj_kernel<<<(N_NODES*HIDDEN + 255)/256, 256, 0, stream>>>(x, agg0, Wp, bp, H);
    // repack weights for both layers
    repack_kernel<<<(2*128*512 + 255)/256, 256, 0, stream>>>(Wf_convs, Ws_convs, Wcat);

    for (int l = 0; l < 2; ++l) {
        const float* Wcat_l = Wcat + (size_t)l * 128 * 512;
        const float* Wfe = Wf_convs + (size_t)l * ZIN * HIDDEN + 256*128;
        const float* Wse = Ws_convs + (size_t)l * ZIN * HIDDEN + 256*128;
        const float* bfl = bf_convs + (size_t)l * HIDDEN;
        const float* bsl = bs_convs + (size_t)l * HIDDEN;
        // P = H @ Wcat_l  (50000 x 128 x 512)
        dim3 ggrid(512/64, (N_NODES + 63)/64);
        gemm64<<<ggrid, 256, 0, stream>>>(H, Wcat_l, P, N_NODES, 512, 128);
        // agg = 0; edge messages
        hipMemsetAsync(agg, 0, (size_t)N_NODES * HIDDEN * sizeof(float), stream);
        edge_kernel<<<2048, 256, 0, stream>>>(P, EA, ei, Wfe, Wse, bfl, bsl, agg);
        // H = relu(H + agg)
        update_kernel<<<(N_NODES*HIDDEN + 255)/256, 256, 0, stream>>>(H, agg);
    }

    // pool + heads
    hipMemsetAsync(gsum, 0, (size_t)(NUM_GRAPHS * HIDDEN + NUM_GRAPHS) * sizeof(float), stream);
    pool_kernel<<<(N_NODES + 127)/128, 128, 0, stream>>>(H, batch, gsum, gcnt);
    head_kernel<<<NUM_GRAPHS, 128, 0, stream>>>(gsum, gcnt, W1, b1, W_heads, b_heads, out);
}